// Round 15
// baseline (169.698 us; speedup 1.0000x reference)
//
#include <hip/hip_runtime.h>
#include <math.h>

// DTM weighted-quantile kernel, v4: dual-output-per-wave ILP (v2 algorithm).
// Evidence r8/r10/r13: v1 31-iter bisect 82.4us @97% VALUBusy (issue-bound);
// v2 ~15-iter value-bisect 79.5us @75% (latency-bound: ~16 serial
// {count -> 6-deep shfl chain -> branch} round trips, ~3 waves/SIMD);
// v3 Illinois 90.9us (heavier serial tail per iter => REGRESSION, reverted).
// v4: each wave processes TWO grid points of the SAME batch in lockstep.
// Two independent count loops + two independent reduce chains interleave in
// the issue slots of one chain's latency => round trips per output halve.
// Per-output phase-1 trajectory is bit-identical to v2 (passed, absmax 0.0).

#define M_POINTS 2048
#define PER_LANE 32  // M_POINTS / 64
#define M0 0.3f

__device__ __forceinline__ float wave_reduce_sum(float v) {
    #pragma unroll
    for (int off = 1; off < 64; off <<= 1)
        v += __shfl_xor(v, off, 64);
    return v;
}
__device__ __forceinline__ float wave_reduce_max(float v) {
    #pragma unroll
    for (int off = 1; off < 64; off <<= 1)
        v = fmaxf(v, __shfl_xor(v, off, 64));
    return v;
}
__device__ __forceinline__ float wave_reduce_min(float v) {
    #pragma unroll
    for (int off = 1; off < 64; off <<= 1)
        v = fminf(v, __shfl_xor(v, off, 64));
    return v;
}

__global__ __launch_bounds__(256) void dtm_kernel(
    const float* __restrict__ inputs,   // [B, M, 2]
    const float* __restrict__ weight,   // [B, M]
    const float* __restrict__ grid,     // [N, 2]
    float* __restrict__ out,            // [B, N]  (f32)
    int B, int N)
{
    const int lane = threadIdx.x & 63;
    const int task = blockIdx.x * (blockDim.x >> 6) + (threadIdx.x >> 6);
    const int halfN = (N + 1) >> 1;
    if (task >= B * halfN) return;        // wave-uniform exit
    const int b  = task / halfN;
    const int r  = task - b * halfN;
    const int n0 = 2 * r;
    const bool has1 = (n0 + 1 < N);
    const int n1 = has1 ? n0 + 1 : n0;    // clamp (duplicate compute, no OOB)

    const float gxa = grid[2 * n0], gya = grid[2 * n0 + 1];
    const float gxb = grid[2 * n1], gyb = grid[2 * n1 + 1];

    const float* __restrict__ inb = inputs + (size_t)b * M_POINTS * 2;
    const float* __restrict__ wb  = weight + (size_t)b * M_POINTS;

    // Contiguous 32 elements per lane -> float4 staging.
    const int base = lane * PER_LANE;
    const float4* __restrict__ xyv = reinterpret_cast<const float4*>(inb + 2 * base);
    const float4* __restrict__ wv  = reinterpret_cast<const float4*>(wb + base);

    float d2a[PER_LANE], d2b[PER_LANE], w[PER_LANE];
    float wsum_local = 0.0f, vmaxa_l = 0.0f, vmaxb_l = 0.0f;
    #pragma unroll
    for (int q = 0; q < PER_LANE / 4; ++q) {
        const float4 wq = wv[q];
        const float4 p0 = xyv[2 * q];       // x0 y0 x1 y1
        const float4 p1 = xyv[2 * q + 1];   // x2 y2 x3 y3
        const float xs[4] = {p0.x, p0.z, p1.x, p1.z};
        const float ys[4] = {p0.y, p0.w, p1.y, p1.w};
        const float ws4[4] = {wq.x, wq.y, wq.z, wq.w};
        #pragma unroll
        for (int t = 0; t < 4; ++t) {
            const int j = 4 * q + t;
            float dx = xs[t] - gxa, dy = ys[t] - gya;
            d2a[j] = fmaf(dx, dx, dy * dy);
            dx = xs[t] - gxb; dy = ys[t] - gyb;
            d2b[j] = fmaf(dx, dx, dy * dy);
            w[j] = ws4[t];
            wsum_local += ws4[t];
            vmaxa_l = fmaxf(vmaxa_l, d2a[j]);
            vmaxb_l = fmaxf(vmaxb_l, d2b[j]);
        }
    }
    const float total = wave_reduce_sum(wsum_local);
    const float bound = M0 * total;       // shared: same batch for both outputs

    // Phase 1: dual value-space bisection (per-output trajectory == v2).
    float vloA = 0.0f, wloA = 0.0f, vhiA = wave_reduce_max(vmaxa_l), whiA = total;
    float vloB = 0.0f, wloB = 0.0f, vhiB = wave_reduce_max(vmaxb_l), whiB = total;
    #pragma unroll 1
    for (int it = 0; it < 48; ++it) {
        const float vmA = 0.5f * (vloA + vhiA);
        const float vmB = 0.5f * (vloB + vhiB);
        const bool actA = (whiA - wloA > 0.75f) && (vmA > vloA) && (vmA < vhiA);
        const bool actB = (whiB - wloB > 0.75f) && (vmB > vloB) && (vmB < vhiB);
        if (!actA && !actB) break;        // wave-uniform
        float cA = 0.0f, cB = 0.0f;
        #pragma unroll
        for (int j = 0; j < PER_LANE; ++j) {
            cA += (d2a[j] <= vmA) ? w[j] : 0.0f;
            cB += (d2b[j] <= vmB) ? w[j] : 0.0f;
        }
        cA = wave_reduce_sum(cA);         // two independent chains -> ILP
        cB = wave_reduce_sum(cB);
        if (actA) { if (cA >= bound) { vhiA = vmA; whiA = cA; }
                    else             { vloA = vmA; wloA = cA; } }
        if (actB) { if (cB >= bound) { vhiB = vmB; whiB = cB; }
                    else             { vloB = vmB; wloB = cB; } }
    }

    // Phase 2: dual exact extraction - find r2 = min value with cnt >= bound.
    float r2A = vhiA, r2B = vhiB;
    bool foundA = false, foundB = false;
    #pragma unroll 1
    for (int step = 0; step < 64; ++step) {
        if (foundA && foundB) break;      // wave-uniform
        float mA = __builtin_inff(), mB = __builtin_inff();
        #pragma unroll
        for (int j = 0; j < PER_LANE; ++j) {
            mA = fminf(mA, (d2a[j] > vloA) ? d2a[j] : __builtin_inff());
            mB = fminf(mB, (d2b[j] > vloB) ? d2b[j] : __builtin_inff());
        }
        mA = wave_reduce_min(mA);
        mB = wave_reduce_min(mB);
        float cA = 0.0f, cB = 0.0f;
        #pragma unroll
        for (int j = 0; j < PER_LANE; ++j) {
            cA += (d2a[j] <= mA) ? w[j] : 0.0f;
            cB += (d2b[j] <= mB) ? w[j] : 0.0f;
        }
        cA = wave_reduce_sum(cA);
        cB = wave_reduce_sum(cB);
        if (!foundA) { if (cA >= bound) { r2A = mA; foundA = true; } else vloA = mA; }
        if (!foundB) { if (cB >= bound) { r2B = mB; foundB = true; } else vloB = mB; }
    }

    // Phase 3: S = sum_{d2<r2} w*d2 and W = sum_{d2<r2} w (direct recompute,
    // same predicate => exactly consistent). Four independent reduce chains.
    float SA = 0.0f, WA = 0.0f, SB = 0.0f, WB = 0.0f;
    #pragma unroll
    for (int j = 0; j < PER_LANE; ++j) {
        if (d2a[j] < r2A) { SA = fmaf(w[j], d2a[j], SA); WA += w[j]; }
        if (d2b[j] < r2B) { SB = fmaf(w[j], d2b[j], SB); WB += w[j]; }
    }
    SA = wave_reduce_sum(SA); WA = wave_reduce_sum(WA);
    SB = wave_reduce_sum(SB); WB = wave_reduce_sum(WB);

    if (lane == 0) {
        const float valA = fmaxf(fmaf(r2A, fmaxf(bound - WA, 0.0f), SA), 0.0f);
        out[(size_t)b * N + n0] = sqrtf(valA / bound);
        if (has1) {
            const float valB = fmaxf(fmaf(r2B, fmaxf(bound - WB, 0.0f), SB), 0.0f);
            out[(size_t)b * N + n0 + 1] = sqrtf(valB / bound);
        }
    }
}

extern "C" void kernel_launch(void* const* d_in, const int* in_sizes, int n_in,
                              void* d_out, int out_size, void* d_ws, size_t ws_size,
                              hipStream_t stream) {
    const float* inputs = (const float*)d_in[0];   // [B, M, 2]
    const float* weight = (const float*)d_in[1];   // [B, M]
    const float* grid   = (const float*)d_in[2];   // [N, 2]
    float* out = (float*)d_out;                    // [B, N] f32

    const int N = in_sizes[2] / 2;                 // 6561
    const int B = out_size / N;                    // 2
    const int halfN = (N + 1) >> 1;                // 3281
    const int total_tasks = B * halfN;             // 6562 wave-tasks

    const int waves_per_block = 256 / 64;
    const int blocks = (total_tasks + waves_per_block - 1) / waves_per_block;

    dtm_kernel<<<blocks, 256, 0, stream>>>(inputs, weight, grid, out, B, N);
}

// Round 17
// 122.826 us; speedup vs baseline: 1.3816x; 1.3816x over previous
//
#include <hip/hip_runtime.h>
#include <math.h>

// DTM weighted-quantile kernel, v5: v2 algorithm + DPP wave reductions.
// Evidence: v1 82.4us @97% VALUBusy; v2 79.5us @75% (latency: ~17 serial
// round trips x 6-deep ds_bpermute chain ~240cy); v3 Illinois 90.9us (worse
// serial tail); v4 dual-output 120.6us (VGPR 108, occupancy 36->16%: bought
// ILP with TLP -- never do that). v5 keeps v2 bit-for-bit but swaps the
// shfl_xor butterfly for the 6-op DPP prefix reduce (row_shr 1/2/4/8,
// row_bcast 15/31, readlane 63): pure-VALU chain ~50cy, zero lgkm in the
// main loop, scalar counts -> scalar branches.

#define M_POINTS 2048
#define PER_LANE 32  // M_POINTS / 64
#define M0 0.3f

// ---- DPP primitives (gfx9/CDNA encodings: row_shr:N=0x110|N, bcast15=0x142,
// bcast31=0x143). update_dpp: lanes w/ invalid source get `old` (bound_ctrl=0)
// or 0 (bound_ctrl=1).
template<int CTRL>
__device__ __forceinline__ float dpp_add_step(float x) {
    union { int i; float f; } u, r;
    u.f = x;
    r.i = __builtin_amdgcn_update_dpp(0, u.i, CTRL, 0xf, 0xf, true); // 0-fill
    return x + r.f;
}
template<int CTRL>
__device__ __forceinline__ float dpp_max_step(float x) {   // valid for x >= 0
    union { int i; float f; } u, r;
    u.f = x;
    r.i = __builtin_amdgcn_update_dpp(0, u.i, CTRL, 0xf, 0xf, true); // 0-fill
    return fmaxf(x, r.f);
}
template<int CTRL>
__device__ __forceinline__ float dpp_min_step(float x) {
    union { int i; float f; } u, r;
    u.f = x;
    r.i = __builtin_amdgcn_update_dpp(0x7F800000, u.i, CTRL, 0xf, 0xf, false); // inf-fill
    return fminf(x, r.f);
}
__device__ __forceinline__ float lane63(float x) {
    union { int i; float f; } u;
    u.f = x;
    u.i = __builtin_amdgcn_readlane(u.i, 63);
    return u.f;                                   // wave-uniform
}
__device__ __forceinline__ float wave_reduce_sum(float x) {
    x = dpp_add_step<0x111>(x);  // row_shr:1
    x = dpp_add_step<0x112>(x);  // row_shr:2
    x = dpp_add_step<0x114>(x);  // row_shr:4
    x = dpp_add_step<0x118>(x);  // row_shr:8  -> lane15/31/47/63 = row sums
    x = dpp_add_step<0x142>(x);  // row_bcast:15 -> lane31/63 = half sums
    x = dpp_add_step<0x143>(x);  // row_bcast:31 -> lane63 = total
    return lane63(x);
}
__device__ __forceinline__ float wave_reduce_max(float x) {
    x = dpp_max_step<0x111>(x);
    x = dpp_max_step<0x112>(x);
    x = dpp_max_step<0x114>(x);
    x = dpp_max_step<0x118>(x);
    x = dpp_max_step<0x142>(x);
    x = dpp_max_step<0x143>(x);
    return lane63(x);
}
__device__ __forceinline__ float wave_reduce_min(float x) {
    x = dpp_min_step<0x111>(x);
    x = dpp_min_step<0x112>(x);
    x = dpp_min_step<0x114>(x);
    x = dpp_min_step<0x118>(x);
    x = dpp_min_step<0x142>(x);
    x = dpp_min_step<0x143>(x);
    return lane63(x);
}

__global__ __launch_bounds__(256) void dtm_kernel(
    const float* __restrict__ inputs,   // [B, M, 2]
    const float* __restrict__ weight,   // [B, M]
    const float* __restrict__ grid,     // [N, 2]
    float* __restrict__ out,            // [B, N]  (f32)
    int B, int N)
{
    const int lane = threadIdx.x & 63;
    const int gwave = blockIdx.x * (blockDim.x >> 6) + (threadIdx.x >> 6);
    if (gwave >= B * N) return;           // wave-uniform exit
    const int b = gwave / N;
    const int n = gwave - b * N;

    const float gx = grid[2 * n];
    const float gy = grid[2 * n + 1];

    const float* __restrict__ inb = inputs + (size_t)b * M_POINTS * 2;
    const float* __restrict__ wb  = weight + (size_t)b * M_POINTS;

    // Contiguous 32 elements per lane -> float4 staging.
    const int base = lane * PER_LANE;
    const float4* __restrict__ xyv = reinterpret_cast<const float4*>(inb + 2 * base);
    const float4* __restrict__ wv  = reinterpret_cast<const float4*>(wb + base);

    float d2[PER_LANE], w[PER_LANE];
    float wsum_local = 0.0f, vmax_local = 0.0f;
    #pragma unroll
    for (int q = 0; q < PER_LANE / 4; ++q) {
        const float4 wq = wv[q];
        const float4 a  = xyv[2 * q];       // x0 y0 x1 y1
        const float4 c4 = xyv[2 * q + 1];   // x2 y2 x3 y3
        float dx, dy;
        dx = a.x  - gx; dy = a.y  - gy; d2[4*q+0] = fmaf(dx, dx, dy * dy);
        dx = a.z  - gx; dy = a.w  - gy; d2[4*q+1] = fmaf(dx, dx, dy * dy);
        dx = c4.x - gx; dy = c4.y - gy; d2[4*q+2] = fmaf(dx, dx, dy * dy);
        dx = c4.z - gx; dy = c4.w - gy; d2[4*q+3] = fmaf(dx, dx, dy * dy);
        w[4*q+0] = wq.x; w[4*q+1] = wq.y; w[4*q+2] = wq.z; w[4*q+3] = wq.w;
        wsum_local += wq.x + wq.y + wq.z + wq.w;
        vmax_local = fmaxf(vmax_local, fmaxf(fmaxf(d2[4*q+0], d2[4*q+1]),
                                             fmaxf(d2[4*q+2], d2[4*q+3])));
    }
    const float total = wave_reduce_sum(wsum_local);
    const float bound = M0 * total;

    // Phase 1: value-space bisection (identical trajectory to v2).
    float vlo = 0.0f, wlo = 0.0f;
    float vhi = wave_reduce_max(vmax_local), whi = total;
    #pragma unroll 1
    for (int it = 0; it < 48; ++it) {
        if (whi - wlo <= 0.75f) break;               // ~<=2 elements remain
        const float vmid = 0.5f * (vlo + vhi);
        if (!(vmid > vlo && vmid < vhi)) break;      // adjacent floats (ties)
        float c = 0.0f;
        #pragma unroll
        for (int j = 0; j < PER_LANE; ++j)
            c += (d2[j] <= vmid) ? w[j] : 0.0f;
        c = wave_reduce_sum(c);
        if (c >= bound) { vhi = vmid; whi = c; }
        else            { vlo = vmid; wlo = c; }     // scalar branch
    }

    // Phase 2: exact extraction - ascending distinct values above vlo.
    float r2 = vhi, W = wlo;
    #pragma unroll 1
    for (int step = 0; step < 64; ++step) {
        float m = __builtin_inff();
        #pragma unroll
        for (int j = 0; j < PER_LANE; ++j)
            m = fminf(m, (d2[j] > vlo) ? d2[j] : __builtin_inff());
        m = wave_reduce_min(m);                      // smallest value > vlo
        float c = 0.0f;
        #pragma unroll
        for (int j = 0; j < PER_LANE; ++j)
            c += (d2[j] <= m) ? w[j] : 0.0f;
        c = wave_reduce_sum(c);
        if (c >= bound) { r2 = m; W = wlo; break; }  // wlo = cnt(values < m)
        vlo = m; wlo = c;
    }

    // Phase 3: S = sum_{d2 < r2} w*d2.
    float S = 0.0f;
    #pragma unroll
    for (int j = 0; j < PER_LANE; ++j)
        if (d2[j] < r2) S = fmaf(w[j], d2[j], S);
    S = wave_reduce_sum(S);

    const float margin = fmaxf(bound - W, 0.0f);     // clamp FP-noise sign flip
    const float val = fmaxf(fmaf(r2, margin, S), 0.0f);
    if (lane == 0) out[gwave] = sqrtf(val / bound);
}

extern "C" void kernel_launch(void* const* d_in, const int* in_sizes, int n_in,
                              void* d_out, int out_size, void* d_ws, size_t ws_size,
                              hipStream_t stream) {
    const float* inputs = (const float*)d_in[0];   // [B, M, 2]
    const float* weight = (const float*)d_in[1];   // [B, M]
    const float* grid   = (const float*)d_in[2];   // [N, 2]
    float* out = (float*)d_out;                    // [B, N] f32

    const int N = in_sizes[2] / 2;                 // 6561
    const int B = out_size / N;                    // 2
    // M hard-wired to 2048 (PER_LANE*64).

    const int total_waves = B * N;                 // 13122
    const int waves_per_block = 256 / 64;
    const int blocks = (total_waves + waves_per_block - 1) / waves_per_block;

    dtm_kernel<<<blocks, 256, 0, stream>>>(inputs, weight, grid, out, B, N);
}